// Round 5
// baseline (297.765 us; speedup 1.0000x reference)
//
#include <hip/hip_runtime.h>
#include <stdint.h>

// Problem constants (B=4, C=256, C8=32, H=W=64, N=4096)
#define NB 4
#define NC 256
#define NC8 32
#define NN 4096

typedef __attribute__((ext_vector_type(8))) short bf16x8;
typedef __attribute__((ext_vector_type(4))) float f32x4;
typedef __attribute__((ext_vector_type(8))) unsigned short u16x8;
typedef __attribute__((ext_vector_type(4))) unsigned short u16x4;

#define MFMA16(a, b, c) __builtin_amdgcn_mfma_f32_16x16x32_bf16((a), (b), (c), 0, 0, 0)
#define LOG2E 1.4426950408889634f

__device__ __forceinline__ unsigned short bf16_rne(float f) {
    unsigned int u = __builtin_bit_cast(unsigned int, f);
    u += 0x7fffu + ((u >> 16) & 1u);
    return (unsigned short)(u >> 16);
}
__device__ __forceinline__ float bf16_to_f(unsigned short h) {
    return __builtin_bit_cast(float, (unsigned int)h << 16);
}
__device__ __forceinline__ float exp2_hw(float x) {
    float r;
    asm("v_exp_f32 %0, %1" : "=v"(r) : "v"(x));
    return r;
}

template <int CTRL>
__device__ __forceinline__ float dpp_mov_f(float v) {
    return __builtin_bit_cast(float,
        __builtin_amdgcn_update_dpp(0, __builtin_bit_cast(int, v), CTRL, 0xf, 0xf, false));
}
__device__ __forceinline__ float rowmax16(float v) {
    v = fmaxf(v, dpp_mov_f<0x128>(v));
    v = fmaxf(v, dpp_mov_f<0x124>(v));
    v = fmaxf(v, dpp_mov_f<0x122>(v));
    v = fmaxf(v, dpp_mov_f<0x121>(v));
    return v;
}
__device__ __forceinline__ float rowsum16(float v) {
    v += dpp_mov_f<0x128>(v);
    v += dpp_mov_f<0x124>(v);
    v += dpp_mov_f<0x122>(v);
    v += dpp_mov_f<0x121>(v);
    return v;
}

__device__ __forceinline__ void async16(const void* g, void* l) {
    __builtin_amdgcn_global_load_lds(
        (const __attribute__((address_space(1))) unsigned int*)g,
        (__attribute__((address_space(3))) unsigned int*)l, 16, 0, 0);
}

// ---------------------------------------------------------------------------
// convert_kernel: fold BN (and LOG2E for q) into w, split hi/lo bf16, store in
// MFMA A-frag order grouped by k-step so proj stages with LINEAR global_load_lds.
// wfrag layout (ushort): [(ks*40 + chunk)*512 + lane*8 + e]
//   chunks per ks: 0-1 q_hi(of0,1) | 2-3 q_lo | 4-5 k_hi | 6-7 k_lo
//                  | 8-23 v_hi(of0..15) | 24-39 v_lo
// biasb: 320 floats (q 0..31 | k 32..63 | v 64..319), BN shift (q incl LOG2E).
// Grid: 40 x 256 — one thread per (row R of 320, c-octet of 32).
// ---------------------------------------------------------------------------
__global__ __launch_bounds__(256) void convert_kernel(
    const float* __restrict__ wq,
    const float* __restrict__ qg, const float* __restrict__ qb,
    const float* __restrict__ qm, const float* __restrict__ qv,
    const float* __restrict__ wk,
    const float* __restrict__ kg, const float* __restrict__ kb,
    const float* __restrict__ km, const float* __restrict__ kv,
    const float* __restrict__ wv,
    const float* __restrict__ vg, const float* __restrict__ vb,
    const float* __restrict__ vm, const float* __restrict__ vv,
    unsigned short* __restrict__ wfrag, float* __restrict__ biasb)
{
    const int idx = blockIdx.x * 256 + threadIdx.x;
    const int R = idx >> 5, oct = idx & 31;
    const float *w, *G, *Bs, *M, *V;
    int o, ch_h, ch_l;
    float mul;
    if (R < 32) {
        o = R; w = wq; G = qg; Bs = qb; M = qm; V = qv; mul = LOG2E;
        ch_h = (o >> 4); ch_l = 2 + (o >> 4);
    } else if (R < 64) {
        o = R - 32; w = wk; G = kg; Bs = kb; M = km; V = kv; mul = 1.0f;
        ch_h = 4 + (o >> 4); ch_l = 6 + (o >> 4);
    } else {
        o = R - 64; w = wv; G = vg; Bs = vb; M = vm; V = vv; mul = 1.0f;
        ch_h = 8 + (o >> 4); ch_l = 24 + (o >> 4);
    }
    const float sc_raw = G[o] / sqrtf(V[o] + 1e-5f);
    const float sc = sc_raw * mul;
    if (oct == 0) biasb[R] = (Bs[o] - M[o] * sc_raw) * mul;

    const int r = o & 15, ks = oct >> 2, g = oct & 3;
    const int lane = g * 16 + r;
    const float* wr = w + o * NC + ks * 32 + g * 8;
    u16x8 hv, lv;
#pragma unroll
    for (int e = 0; e < 8; ++e) {
        float wv_ = wr[e] * sc;
        unsigned short h = bf16_rne(wv_);
        hv[e] = h;
        lv[e] = bf16_rne(wv_ - bf16_to_f(h));
    }
    *(u16x8*)&wfrag[(size_t)(ks * 40 + ch_h) * 512 + lane * 8] = hv;
    *(u16x8*)&wfrag[(size_t)(ks * 40 + ch_l) * 512 + lane * 8] = lv;
}

// ---------------------------------------------------------------------------
// proj_kernel v2 (MFMA): D[o][n] = w'·x, x split hi/lo in-reg (3-term MFMA).
// Block = 64 n-cols (wave w owns n-frag w), all 320 o-rows. Grid 256 x 256.
// w-frags staged per k-step from wfrag (linear global_load_lds, lane*16B reads
// — conflict-free), double-buffered 2x40KB.
// ---------------------------------------------------------------------------
__global__ __launch_bounds__(256, 1) void proj_kernel(
    const float* __restrict__ x,
    const unsigned short* __restrict__ wfrag,
    const float* __restrict__ biasb,
    unsigned short* __restrict__ qhi, unsigned short* __restrict__ qlo,
    unsigned short* __restrict__ khi, unsigned short* __restrict__ klo,
    unsigned short* __restrict__ vws)
{
    __shared__ __align__(16) char wl[81920];
    const int t = threadIdx.x;
    const int w = t >> 6, lane = t & 63, g = lane >> 4, r = lane & 15;
    const int b = blockIdx.x >> 6;
    const int n0 = (blockIdx.x & 63) << 6;
    const int n_lane = n0 + w * 16 + r;
    const float* xb = x + ((size_t)b << 20);

    // x B-frags: lane (g,r) holds x[c = ks*32+g*8+e][n_lane], hi/lo split
    bf16x8 bxh[8], bxl[8];
#pragma unroll
    for (int ks = 0; ks < 8; ++ks)
#pragma unroll
        for (int e = 0; e < 8; ++e) {
            float xv = xb[((size_t)(ks * 32 + g * 8 + e) << 12) + n_lane];
            unsigned short h = bf16_rne(xv);
            bxh[ks][e] = (short)h;
            bxl[ks][e] = (short)bf16_rne(xv - bf16_to_f(h));
        }

    auto stage = [&](int ks, int buf) {
        char* base = wl + buf * 40960;
        for (int ch = w; ch < 40; ch += 4)
            async16(wfrag + (size_t)(ks * 40 + ch) * 512 + lane * 8,
                    base + ch * 1024);
    };

    f32x4 aq[2], ak[2], av[16];
#pragma unroll
    for (int of = 0; of < 2; ++of) {
        aq[of] = (f32x4){0.f, 0.f, 0.f, 0.f};
        ak[of] = (f32x4){0.f, 0.f, 0.f, 0.f};
    }
#pragma unroll
    for (int of = 0; of < 16; ++of) av[of] = (f32x4){0.f, 0.f, 0.f, 0.f};

    stage(0, 0);
    __syncthreads();
    for (int ks = 0; ks < 8; ++ks) {
        const int buf = ks & 1;
        if (ks < 7) stage(ks + 1, buf ^ 1);
        const char* base = wl + buf * 40960;
        auto frag = [&](int ch) {
            return *(const bf16x8*)(base + ch * 1024 + lane * 16);
        };
#pragma unroll
        for (int of = 0; of < 2; ++of) {
            bf16x8 ah = frag(of), al = frag(2 + of);
            aq[of] = MFMA16(ah, bxh[ks], aq[of]);
            aq[of] = MFMA16(ah, bxl[ks], aq[of]);
            aq[of] = MFMA16(al, bxh[ks], aq[of]);
        }
#pragma unroll
        for (int of = 0; of < 2; ++of) {
            bf16x8 ah = frag(4 + of), al = frag(6 + of);
            ak[of] = MFMA16(ah, bxh[ks], ak[of]);
            ak[of] = MFMA16(ah, bxl[ks], ak[of]);
            ak[of] = MFMA16(al, bxh[ks], ak[of]);
        }
#pragma unroll
        for (int of = 0; of < 16; ++of) {
            bf16x8 ah = frag(8 + of), al = frag(24 + of);
            av[of] = MFMA16(ah, bxh[ks], av[of]);
            av[of] = MFMA16(ah, bxl[ks], av[of]);
            av[of] = MFMA16(al, bxh[ks], av[of]);
        }
        __syncthreads();
    }

    // epilogue: D-frag lane (g,r): rows o = of*16+g*4+e, col n = n_lane
    const size_t qbase = ((size_t)(b << 12) + n_lane) * 32;
#pragma unroll
    for (int of = 0; of < 2; ++of) {
        const int ob = of * 16 + g * 4;
        u16x4 hq, lq, hk, lk;
#pragma unroll
        for (int e = 0; e < 4; ++e) {
            float val = aq[of][e] + biasb[ob + e];
            unsigned short h = bf16_rne(val);
            hq[e] = h; lq[e] = bf16_rne(val - bf16_to_f(h));
            float vk = ak[of][e] + biasb[32 + ob + e];
            unsigned short hh = bf16_rne(vk);
            hk[e] = hh; lk[e] = bf16_rne(vk - bf16_to_f(hh));
        }
        *(u16x4*)&qhi[qbase + ob] = hq;
        *(u16x4*)&qlo[qbase + ob] = lq;
        *(u16x4*)&khi[qbase + ob] = hk;
        *(u16x4*)&klo[qbase + ob] = lk;
    }
#pragma unroll
    for (int of = 0; of < 16; ++of)
#pragma unroll
        for (int e = 0; e < 4; ++e) {
            const int o = of * 16 + g * 4 + e;
            float val = av[of][e] + biasb[64 + o];
            vws[((size_t)(b * NC + o) << 12) + n_lane] = bf16_rne(val);
        }
}

// ---------------------------------------------------------------------------
// Flash attention kernel v3: 512 blocks x 512 threads (8 waves).
// Block = 32 q-rows x 256 c. Wave (wi = w>>2, wc = w&3): rows i0+wi*16..+15,
// cols wc*64..+63 (1 i-frag x 4 c-frags). 16 waves/CU (2 blocks).
// LDS: 2x20KB staged {Khi 2K|Klo 2K|V 16K} (XOR-swizzled via global source),
// 8x1280B per-wave P ([16][40] ushorts: 16B-aligned rows, <=2-way banks).
// 40960 + 8*1280 = 51200 = sizeof(smem) exactly (R3 bug: stride 2560 -> OOB).
// ---------------------------------------------------------------------------
__global__ __launch_bounds__(512, 4) void attn_kernel(
    const float* __restrict__ x, const float* __restrict__ gamma_p,
    const unsigned short* __restrict__ qhi, const unsigned short* __restrict__ qlo,
    const unsigned short* __restrict__ khi, const unsigned short* __restrict__ klo,
    const unsigned short* __restrict__ vws,
    float* __restrict__ out)
{
    __shared__ __align__(16) char smem[51200];
    const int t = threadIdx.x;
    const int pb = blockIdx.x;
    const int xcd = pb & 7;
    const int b = xcd >> 1;
    const int tile = ((xcd & 1) << 6) + (pb >> 3);
    const int i0 = tile << 5;
    const int w = t >> 6, lane = t & 63;
    const int g = lane >> 4, r = lane & 15;
    const int wi = w >> 2, wc = w & 3;

    const size_t bN32 = (size_t)b * (NN * 32);
    const unsigned short* kh_g = khi + bN32;
    const unsigned short* kl_g = klo + bN32;
    const unsigned short* v_g = vws + (size_t)b * (NC * NN);

    bf16x8 qh, ql;
    {
        size_t off = bN32 + (size_t)(i0 + wi * 16 + r) * 32 + g * 8;
        qh = *(const bf16x8*)&qhi[off];
        ql = *(const bf16x8*)&qlo[off];
    }

    f32x4 acc[4];
#pragma unroll
    for (int fc = 0; fc < 4; ++fc) acc[fc] = (f32x4){0.f, 0.f, 0.f, 0.f};
    float m_run[4], l_part[4];
#pragma unroll
    for (int e = 0; e < 4; ++e) { m_run[e] = -3.0e38f; l_part[e] = 0.f; }

    auto stage = [&](int jt, int buf) {
        char* base = smem + buf * 20480;
        const int j0 = jt << 5;
        for (int cidx = w; cidx < 20; cidx += 8) {
            const unsigned short* gs;
            if (cidx < 4) {
                int row = ((cidx & 1) << 4) + (lane >> 2);
                int gl = (lane & 3) ^ ((row >> 1) & 3);
                gs = (cidx < 2 ? kh_g : kl_g) + (size_t)(j0 + row) * 32 + (gl << 3);
            } else {
                int c = ((cidx - 4) << 4) + (lane >> 2);
                int gl = (lane & 3) ^ ((c >> 1) & 3);
                gs = v_g + ((size_t)c << 12) + j0 + (gl << 3);
            }
            async16(gs, base + cidx * 1024);
        }
    };

    stage(0, 0);
    __syncthreads();

    for (int jt = 0; jt < NN / 32; ++jt) {
        const int buf = jt & 1;
        if (jt < NN / 32 - 1) stage(jt + 1, buf ^ 1);

        const char* base = smem + buf * 20480;
        const unsigned short* Kh = (const unsigned short*)(base);
        const unsigned short* Kl = (const unsigned short*)(base + 2048);
        const unsigned short* Vl = (const unsigned short*)(base + 4096);

        // ---- S = Q K^T (hi/lo split, fp32 acc, log2 domain) ----
        bf16x8 kfh[2], kfl[2];
#pragma unroll
        for (int fj = 0; fj < 2; ++fj) {
            int row = fj * 16 + r;
            int off = (row << 5) + ((g ^ ((row >> 1) & 3)) << 3);
            kfh[fj] = *(const bf16x8*)&Kh[off];
            kfl[fj] = *(const bf16x8*)&Kl[off];
        }
        f32x4 s[2];
#pragma unroll
        for (int fj = 0; fj < 2; ++fj) {
            f32x4 z = (f32x4){0.f, 0.f, 0.f, 0.f};
            z = MFMA16(qh, kfl[fj], z);
            z = MFMA16(ql, kfh[fj], z);
            z = MFMA16(qh, kfh[fj], z);
            s[fj] = z;
        }

        // ---- online softmax (log2 domain) ----
        float tm[4];
#pragma unroll
        for (int e = 0; e < 4; ++e) tm[e] = rowmax16(fmaxf(s[0][e], s[1][e]));

        bool okf = true;
#pragma unroll
        for (int e = 0; e < 4; ++e) okf = okf && (tm[e] <= m_run[e] + 11.0f);
        if (!__all(okf)) {
            float rs[4];
#pragma unroll
            for (int e = 0; e < 4; ++e) {
                float nm = fmaxf(m_run[e], tm[e]);
                rs[e] = exp2_hw(m_run[e] - nm);
                m_run[e] = nm;
                l_part[e] *= rs[e];
            }
#pragma unroll
            for (int fc = 0; fc < 4; ++fc)
#pragma unroll
                for (int e = 0; e < 4; ++e) acc[fc][e] *= rs[e];
        }

        float p[2][4];
#pragma unroll
        for (int fj = 0; fj < 2; ++fj)
#pragma unroll
            for (int e = 0; e < 4; ++e)
                p[fj][e] = exp2_hw(s[fj][e] - m_run[e]);
#pragma unroll
        for (int e = 0; e < 4; ++e) l_part[e] += p[0][e] + p[1][e];

        // ---- P: D-frag -> bf16 -> per-wave LDS [16][40] (stride-40) ----
        unsigned short* P = (unsigned short*)(smem + 40960 + w * 1280);
#pragma unroll
        for (int fj = 0; fj < 2; ++fj)
#pragma unroll
            for (int e = 0; e < 4; ++e)
                P[(g * 4 + e) * 40 + fj * 16 + r] = bf16_rne(p[fj][e]);
        asm volatile("s_waitcnt lgkmcnt(0)" ::: "memory");
        __builtin_amdgcn_sched_barrier(0);

        // ---- PV: acc += P[16x32] * V[32x16 per c-frag] ----
        bf16x8 pa = *(const bf16x8*)&P[r * 40 + g * 8];
#pragma unroll
        for (int fc = 0; fc < 4; ++fc) {
            int c = (wc << 6) + (fc << 4) + r;
            bf16x8 vbf = *(const bf16x8*)&Vl[(c << 5) + ((g ^ ((c >> 1) & 3)) << 3)];
            acc[fc] = MFMA16(pa, vbf, acc[fc]);
        }
        __syncthreads();
    }

    // ---- epilogue: out = gamma * acc/l + x, transpose through swizzled LDS ----
    const float gm = gamma_p[0];
    float linv[4];
#pragma unroll
    for (int e = 0; e < 4; ++e) linv[e] = gm / rowsum16(l_part[e]);

    __syncthreads();
    char* ep = smem;  // [c 0..255][8 slots of 16B], slot ^= (c&7)
#pragma unroll
    for (int fc = 0; fc < 4; ++fc) {
        int c = (wc << 6) + (fc << 4) + r;
        int islot = wi * 4 + g;
        float* dst = (float*)(ep + (c << 7) + ((islot ^ (c & 7)) << 4));
#pragma unroll
        for (int e = 0; e < 4; ++e) dst[e] = acc[fc][e] * linv[e];
    }
    __syncthreads();

    const float* xb = x + ((size_t)b << 20);
    float* ob = out + ((size_t)b << 20);
#pragma unroll
    for (int it = 0; it < 4; ++it) {
        int c = (t >> 3) + (it << 6);
        int j = t & 7;
        int islot = j ^ (c & 7);
        f32x4 v = *(const f32x4*)(ep + (c << 7) + (j << 4));
        f32x4 xv = *(const f32x4*)&xb[((size_t)c << 12) + i0 + islot * 4];
        v += xv;
        *(f32x4*)&ob[((size_t)c << 12) + i0 + islot * 4] = v;
    }
}

// ---------------------------------------------------------------------------
extern "C" void kernel_launch(void* const* d_in, const int* in_sizes, int n_in,
                              void* d_out, int out_size, void* d_ws, size_t ws_size,
                              hipStream_t stream)
{
    (void)in_sizes; (void)n_in; (void)out_size; (void)ws_size;
    const float* x = (const float*)d_in[0];
    const float* wq = (const float*)d_in[1];
    const float* qg = (const float*)d_in[2];
    const float* qb = (const float*)d_in[3];
    const float* qm = (const float*)d_in[4];
    const float* qv = (const float*)d_in[5];
    const float* wk = (const float*)d_in[6];
    const float* kg = (const float*)d_in[7];
    const float* kb = (const float*)d_in[8];
    const float* km = (const float*)d_in[9];
    const float* kv = (const float*)d_in[10];
    const float* wv = (const float*)d_in[11];
    const float* vg = (const float*)d_in[12];
    const float* vb = (const float*)d_in[13];
    const float* vm = (const float*)d_in[14];
    const float* vv = (const float*)d_in[15];
    const float* gamma = (const float*)d_in[16];

    unsigned short* ws = (unsigned short*)d_ws;
    const size_t QK = (size_t)NB * NN * 32;       // 524288
    const size_t VSZ = (size_t)NB * NC * NN;      // 4194304
    unsigned short* qhi = ws;
    unsigned short* qlo = ws + QK;
    unsigned short* khi = ws + 2 * QK;
    unsigned short* klo = ws + 3 * QK;
    unsigned short* vws = ws + 4 * QK;
    unsigned short* wfrag = ws + 4 * QK + VSZ;    // 163840 ushorts
    float* biasb = (float*)(wfrag + 163840);      // 320 floats

    convert_kernel<<<dim3(40), dim3(256), 0, stream>>>(
        wq, qg, qb, qm, qv, wk, kg, kb, km, kv, wv, vg, vb, vm, vv,
        wfrag, biasb);
    proj_kernel<<<dim3(256), dim3(256), 0, stream>>>(
        x, wfrag, biasb, qhi, qlo, khi, klo, vws);
    attn_kernel<<<dim3(512), dim3(512), 0, stream>>>(
        x, gamma, qhi, qlo, khi, klo, vws, (float*)d_out);
}

// Round 6
// 174.589 us; speedup vs baseline: 1.7055x; 1.7055x over previous
//
#include <hip/hip_runtime.h>
#include <stdint.h>

// Problem constants (B=4, C=256, C8=32, H=W=64, N=4096)
#define NB 4
#define NC 256
#define NN 4096

typedef __attribute__((ext_vector_type(8))) short bf16x8;
typedef __attribute__((ext_vector_type(4))) float f32x4;
typedef __attribute__((ext_vector_type(8))) unsigned short u16x8;
typedef __attribute__((ext_vector_type(4))) unsigned short u16x4;
typedef __attribute__((ext_vector_type(4))) unsigned int u32x4;

#define MFMA16(a, b, c) __builtin_amdgcn_mfma_f32_16x16x32_bf16((a), (b), (c), 0, 0, 0)
#define LOG2E 1.4426950408889634f

__device__ __forceinline__ unsigned short bf16_rne(float f) {
    unsigned int u = __builtin_bit_cast(unsigned int, f);
    u += 0x7fffu + ((u >> 16) & 1u);
    return (unsigned short)(u >> 16);
}
__device__ __forceinline__ float bf16_to_f(unsigned short h) {
    return __builtin_bit_cast(float, (unsigned int)h << 16);
}
__device__ __forceinline__ float exp2_hw(float x) {
    float r;
    asm("v_exp_f32 %0, %1" : "=v"(r) : "v"(x));
    return r;
}
__device__ __forceinline__ unsigned int cvtpk_bf16(float lo, float hi) {
    unsigned int r;
    asm("v_cvt_pk_bf16_f32 %0, %1, %2" : "=v"(r) : "v"(lo), "v"(hi));
    return r;
}

__device__ __forceinline__ void async16(const void* g, void* l) {
    __builtin_amdgcn_global_load_lds(
        (const __attribute__((address_space(1))) unsigned int*)g,
        (__attribute__((address_space(3))) unsigned int*)l, 16, 0, 0);
}

// ---------------------------------------------------------------------------
// Projection kernel (R2 version, verbatim): q,k (fp32 -> bf16 hi/lo split) and
// v (bf16), BN folded; q additionally scaled by log2(e) for exp2 softmax.
// q_hi/q_lo/k_hi/k_lo layout: [B][N][32] bf16 ; v layout: [B][256][N] bf16.
// Grid: 512 blocks x 256 threads; block handles 32 spatial positions.
// ---------------------------------------------------------------------------
__global__ __launch_bounds__(256) void proj_kernel(
    const float* __restrict__ x,
    const float* __restrict__ wq,
    const float* __restrict__ qg, const float* __restrict__ qb,
    const float* __restrict__ qm, const float* __restrict__ qv,
    const float* __restrict__ wk,
    const float* __restrict__ kg, const float* __restrict__ kb,
    const float* __restrict__ km, const float* __restrict__ kv,
    const float* __restrict__ wv,
    const float* __restrict__ vg, const float* __restrict__ vb,
    const float* __restrict__ vm, const float* __restrict__ vv,
    unsigned short* __restrict__ qhi, unsigned short* __restrict__ qlo,
    unsigned short* __restrict__ khi, unsigned short* __restrict__ klo,
    unsigned short* __restrict__ vws)
{
    __shared__ float xt[NC * 36 + 8];
    const int t = threadIdx.x;
    const int blk = blockIdx.x;
    const int b = blk >> 7;
    const int n0 = (blk & 127) << 5;
    const float* xb = x + ((size_t)b << 20);

    for (int idx = t; idx < NC * 32; idx += 256) {
        int c = idx >> 5, j = idx & 31;
        xt[c * 36 + j] = xb[((size_t)c << 12) + n0 + j];
    }
    __syncthreads();

    {
        const int p = t & 31;
        const int og = t >> 5;
        const bool is_k = og >= 4;
        const int o0 = (og & 3) << 3;
        const float* w = is_k ? wk : wq;
        float acc[8];
#pragma unroll
        for (int o = 0; o < 8; ++o) acc[o] = 0.f;
        for (int c4 = 0; c4 < NC; c4 += 4) {
            float x0 = xt[(c4 + 0) * 36 + p];
            float x1 = xt[(c4 + 1) * 36 + p];
            float x2 = xt[(c4 + 2) * 36 + p];
            float x3 = xt[(c4 + 3) * 36 + p];
#pragma unroll
            for (int o = 0; o < 8; ++o) {
                const float4 w4 = *(const float4*)&w[(o0 + o) * NC + c4];
                acc[o] += w4.x * x0 + w4.y * x1 + w4.z * x2 + w4.w * x3;
            }
        }
        const float* G = is_k ? kg : qg;
        const float* Bb = is_k ? kb : qb;
        const float* M = is_k ? km : qm;
        const float* V = is_k ? kv : qv;
        u16x8 hv, lv;
#pragma unroll
        for (int o = 0; o < 8; ++o) {
            int oo = o0 + o;
            float sc = G[oo] / sqrtf(V[oo] + 1e-5f);
            float val = acc[o] * sc + (Bb[oo] - M[oo] * sc);
            if (!is_k) val *= LOG2E;
            unsigned short h = bf16_rne(val);
            hv[o] = h;
            lv[o] = bf16_rne(val - bf16_to_f(h));
        }
        size_t base = ((size_t)(b << 12) + n0 + p) * 32 + o0;
        *(u16x8*)&(is_k ? khi : qhi)[base] = hv;
        *(u16x8*)&(is_k ? klo : qlo)[base] = lv;
    }

    {
        const int p4 = (t & 7) << 2;
        const int og = t >> 3;
        const int o0 = og << 3;
        float acc[4][8];
#pragma unroll
        for (int pp = 0; pp < 4; ++pp)
#pragma unroll
            for (int o = 0; o < 8; ++o) acc[pp][o] = 0.f;
        for (int c4 = 0; c4 < NC; c4 += 4) {
            float4 xv0 = *(const float4*)&xt[(c4 + 0) * 36 + p4];
            float4 xv1 = *(const float4*)&xt[(c4 + 1) * 36 + p4];
            float4 xv2 = *(const float4*)&xt[(c4 + 2) * 36 + p4];
            float4 xv3 = *(const float4*)&xt[(c4 + 3) * 36 + p4];
#pragma unroll
            for (int o = 0; o < 8; ++o) {
                const float4 w4 = *(const float4*)&wv[(o0 + o) * NC + c4];
                acc[0][o] += w4.x * xv0.x + w4.y * xv1.x + w4.z * xv2.x + w4.w * xv3.x;
                acc[1][o] += w4.x * xv0.y + w4.y * xv1.y + w4.z * xv2.y + w4.w * xv3.y;
                acc[2][o] += w4.x * xv0.z + w4.y * xv1.z + w4.z * xv2.z + w4.w * xv3.z;
                acc[3][o] += w4.x * xv0.w + w4.y * xv1.w + w4.z * xv2.w + w4.w * xv3.w;
            }
        }
#pragma unroll
        for (int o = 0; o < 8; ++o) {
            int oo = o0 + o;
            float sc = vg[oo] / sqrtf(vv[oo] + 1e-5f);
            float sh = vb[oo] - vm[oo] * sc;
            u16x4 st;
#pragma unroll
            for (int pp = 0; pp < 4; ++pp) st[pp] = bf16_rne(acc[pp][o] * sc + sh);
            *(u16x4*)&vws[((size_t)(b * NC + oo) << 12) + n0 + p4] = st;
        }
    }
}

// ---------------------------------------------------------------------------
// Flash attention v4: swapped QK^T (P lane-local per q-row), KVBLK=64,
// 512 blocks x 512 threads (8 waves = 2 wi x 2 wc x 2 wjp).
// Wave (wi,wc,wjp): q-rows i0+wi*16..+15, c-cols wc*128..+127, j-half wjp.
// K LDS rows PERMUTED at stage (j' = 8g+4fj+e) so the swapped-QK output is
// already in PV A-frag order -> zero cross-lane shuffles for P.
// Per-wave partial (m,l,acc) over its j-half; merged across wjp in epilogue.
// LDS: 2 x 40KB staging {Khi 4K | Klo 4K | V 32K}; epilogue reuses it.
// ---------------------------------------------------------------------------
__global__ __launch_bounds__(512, 4) void attn_kernel(
    const float* __restrict__ x, const float* __restrict__ gamma_p,
    const unsigned short* __restrict__ qhi, const unsigned short* __restrict__ qlo,
    const unsigned short* __restrict__ khi, const unsigned short* __restrict__ klo,
    const unsigned short* __restrict__ vws,
    float* __restrict__ out)
{
    __shared__ __align__(16) char smem[81920];
    const int t = threadIdx.x;
    const int pb = blockIdx.x;
    const int xcd = pb & 7;
    const int b = xcd >> 1;
    const int tile = ((xcd & 1) << 6) + (pb >> 3);
    const int i0 = tile << 5;
    const int w = t >> 6, lane = t & 63;
    const int g = lane >> 4, r = lane & 15;
    const int wi = w & 1, wc = (w >> 1) & 1, wjp = (w >> 2) & 1;

    const size_t bN32 = (size_t)b * (NN * 32);
    const unsigned short* kh_g = khi + bN32;
    const unsigned short* kl_g = klo + bN32;
    const unsigned short* v_g = vws + (size_t)b * (NC * NN);

    // Q fragment (serves as MFMA B-operand in swapped QK^T):
    // lane (g,r) holds Q[row i0+wi*16+r][k = g*8..+7]
    bf16x8 qh, ql;
    {
        size_t off = bN32 + (size_t)(i0 + wi * 16 + r) * 32 + g * 8;
        qh = *(const bf16x8*)&qhi[off];
        ql = *(const bf16x8*)&qlo[off];
    }

    f32x4 acc[8];
#pragma unroll
    for (int fc = 0; fc < 8; ++fc) acc[fc] = (f32x4){0.f, 0.f, 0.f, 0.f};
    float m_run = -3.0e38f, l_part = 0.f;   // per lane: q-row i = r (replicated over g)

    // stage one 64-j tile (40 chunks of 1KB: Khi 0-3 | Klo 4-7 | V 8-39).
    // K storage row s holds global j = j0 + (s>>5)*32 + permj(s&31), where
    // permj(16fj+4g+e) = 8g+4fj+e  (makes swapped-QK output land in A-frag order).
    // 16B col-slots XOR-swizzled via the global source (rule 21).
    auto stage = [&](int jt, int bufi) {
        char* base = smem + bufi * 40960;
        const int j0 = jt << 6;
#pragma unroll
        for (int ci = 0; ci < 5; ++ci) {
            const int cidx = w + ci * 8;
            const unsigned short* gs;
            if (cidx < 8) {
                int kind = cidx >> 2;                    // 0 = hi, 1 = lo
                int s = ((cidx & 3) << 4) + (lane >> 2); // storage row 0..63
                int u = s & 31;
                int jsrc = j0 + ((s >> 5) << 5)
                         + ((((u >> 2) & 3) << 3) | (((u >> 4) & 1) << 2) | (u & 3));
                int lg = (lane & 3) ^ ((s >> 1) & 3);
                gs = (kind ? kl_g : kh_g) + (size_t)jsrc * 32 + (lg << 3);
            } else {
                int cv = cidx - 8;
                int c = (cv << 3) + (lane >> 3);         // c-row 0..255
                int jslot = (lane & 7) ^ (c & 7);        // 8 ushorts per slot
                gs = v_g + ((size_t)c << 12) + j0 + (jslot << 3);
            }
            async16(gs, base + cidx * 1024);
        }
    };

    stage(0, 0);
    __syncthreads();

    for (int jt = 0; jt < NN / 64; ++jt) {
        const int buf = jt & 1;
        if (jt < NN / 64 - 1) stage(jt + 1, buf ^ 1);

        const char* base = smem + buf * 40960;
        const unsigned short* Kh = (const unsigned short*)(base);
        const unsigned short* Kl = (const unsigned short*)(base + 4096);
        const unsigned short* Vl = (const unsigned short*)(base + 8192);

        // ---- S^T = K Q (hi/lo split): lane (g,r) -> S[j' = 8g+4fj+e][i = r] ----
        f32x4 s2[2];
#pragma unroll
        for (int fj = 0; fj < 2; ++fj) {
            int sr = wjp * 32 + fj * 16 + r;
            int off = sr * 32 + ((g ^ ((r >> 1) & 3)) << 3);
            bf16x8 kfh = *(const bf16x8*)&Kh[off];
            bf16x8 kfl = *(const bf16x8*)&Kl[off];
            f32x4 z = (f32x4){0.f, 0.f, 0.f, 0.f};
            z = MFMA16(kfl, qh, z);
            z = MFMA16(kfh, ql, z);
            z = MFMA16(kfh, qh, z);
            s2[fj] = z;
        }

        // ---- online softmax, log2 domain; row = this lane's i = r ----
        float tl = fmaxf(fmaxf(fmaxf(s2[0][0], s2[0][1]), fmaxf(s2[0][2], s2[0][3])),
                         fmaxf(fmaxf(s2[1][0], s2[1][1]), fmaxf(s2[1][2], s2[1][3])));
        tl = fmaxf(tl, __shfl_xor(tl, 16));
        tl = fmaxf(tl, __shfl_xor(tl, 32));

        if (!__all(tl <= m_run + 11.0f)) {
            float nm = fmaxf(m_run, tl);
            float rs = exp2_hw(m_run - nm);
            m_run = nm;
            l_part *= rs;
            float rse[4];
#pragma unroll
            for (int e = 0; e < 4; ++e) rse[e] = __shfl(rs, g * 4 + e);
#pragma unroll
            for (int fc = 0; fc < 8; ++fc)
#pragma unroll
                for (int e = 0; e < 4; ++e) acc[fc][e] *= rse[e];
        }

        float p[2][4];
#pragma unroll
        for (int fj = 0; fj < 2; ++fj)
#pragma unroll
            for (int e = 0; e < 4; ++e)
                p[fj][e] = exp2_hw(s2[fj][e] - m_run);
        float ls = ((p[0][0] + p[0][1]) + (p[0][2] + p[0][3]))
                 + ((p[1][0] + p[1][1]) + (p[1][2] + p[1][3]));
        ls += __shfl_xor(ls, 16);
        ls += __shfl_xor(ls, 32);
        l_part += ls;

        // ---- P -> bf16 A-frag (already in j-order thanks to K permutation) ----
        u32x4 pw;
        pw[0] = cvtpk_bf16(p[0][0], p[0][1]);
        pw[1] = cvtpk_bf16(p[0][2], p[0][3]);
        pw[2] = cvtpk_bf16(p[1][0], p[1][1]);
        pw[3] = cvtpk_bf16(p[1][2], p[1][3]);
        bf16x8 pa = __builtin_bit_cast(bf16x8, pw);

        // ---- PV: acc[fc] += P[16i x 32j] * V[32j x 16c] ----
#pragma unroll
        for (int fc = 0; fc < 8; ++fc) {
            int c = wc * 128 + fc * 16 + r;
            bf16x8 vbf = *(const bf16x8*)&Vl[c * 64 + ((((wjp << 2) + g) ^ (r & 7)) << 3)];
            acc[fc] = MFMA16(pa, vbf, acc[fc]);
        }
        __syncthreads();   // drains stage(jt+1) + protects buffer swap
    }

    // ---- merge wjp partials, normalize, residual-add, store ----
    float* ml = (float*)smem;                 // m: [w*16+r], l: [128 + w*16+r]
    if (g == 0) {
        ml[w * 16 + r] = m_run;
        ml[128 + w * 16 + r] = l_part;
    }
    __syncthreads();

    const int wp = w ^ 4;                     // partner wave (wjp flipped)
    float m_o = ml[wp * 16 + r];
    float l_o = ml[128 + wp * 16 + r];
    float m_g = fmaxf(m_run, m_o);
    float a_s = exp2_hw(m_run - m_g);
    float l_tot = l_part * a_s + l_o * exp2_hw(m_o - m_g);
    {
        float ase[4];
#pragma unroll
        for (int e = 0; e < 4; ++e) ase[e] = __shfl(a_s, g * 4 + e);
#pragma unroll
        for (int fc = 0; fc < 8; ++fc)
#pragma unroll
            for (int e = 0; e < 4; ++e) acc[fc][e] *= ase[e];
    }

    float* AB = (float*)(smem + 4096);        // [q2(wi,wc)][16 i][128 c]
    const int q2 = wi * 2 + wc;
    if (wjp == 1) {
#pragma unroll
        for (int fc = 0; fc < 8; ++fc)
#pragma unroll
            for (int e = 0; e < 4; ++e)
                AB[(q2 * 16 + g * 4 + e) * 128 + fc * 16 + r] = acc[fc][e];
    }
    __syncthreads();

    if (wjp == 0) {
        const float gm = gamma_p[0];
        float linv = gm / l_tot;
        float le[4];
#pragma unroll
        for (int e = 0; e < 4; ++e) le[e] = __shfl(linv, g * 4 + e);
        char* ep = smem + 40960;              // [c 0..255][8 slots of 16B], slot ^= (c&7)
#pragma unroll
        for (int fc = 0; fc < 8; ++fc) {
            int c = wc * 128 + fc * 16 + r;
            int islot = wi * 4 + g;
            float* dst = (float*)(ep + (c << 7) + ((islot ^ (c & 7)) << 4));
#pragma unroll
            for (int e = 0; e < 4; ++e)
                dst[e] = (acc[fc][e] + AB[(q2 * 16 + g * 4 + e) * 128 + fc * 16 + r]) * le[e];
        }
    }
    __syncthreads();

    const char* ep = smem + 40960;
    const float* xb = x + ((size_t)b << 20);
    float* ob = out + ((size_t)b << 20);
#pragma unroll
    for (int it = 0; it < 4; ++it) {
        int c = (t >> 3) + (it << 6);
        int j = t & 7;
        int islot = j ^ (c & 7);
        f32x4 v = *(const f32x4*)(ep + (c << 7) + (j << 4));
        f32x4 xv = *(const f32x4*)&xb[((size_t)c << 12) + i0 + islot * 4];
        v += xv;
        *(f32x4*)&ob[((size_t)c << 12) + i0 + islot * 4] = v;
    }
}

// ---------------------------------------------------------------------------
extern "C" void kernel_launch(void* const* d_in, const int* in_sizes, int n_in,
                              void* d_out, int out_size, void* d_ws, size_t ws_size,
                              hipStream_t stream)
{
    (void)in_sizes; (void)n_in; (void)out_size; (void)ws_size;
    const float* x = (const float*)d_in[0];
    const float* wq = (const float*)d_in[1];
    const float* qg = (const float*)d_in[2];
    const float* qb = (const float*)d_in[3];
    const float* qm = (const float*)d_in[4];
    const float* qv = (const float*)d_in[5];
    const float* wk = (const float*)d_in[6];
    const float* kg = (const float*)d_in[7];
    const float* kb = (const float*)d_in[8];
    const float* km = (const float*)d_in[9];
    const float* kv = (const float*)d_in[10];
    const float* wv = (const float*)d_in[11];
    const float* vg = (const float*)d_in[12];
    const float* vb = (const float*)d_in[13];
    const float* vm = (const float*)d_in[14];
    const float* vv = (const float*)d_in[15];
    const float* gamma = (const float*)d_in[16];

    unsigned short* ws = (unsigned short*)d_ws;
    const size_t QK = (size_t)NB * NN * 32;
    unsigned short* qhi = ws;
    unsigned short* qlo = ws + QK;
    unsigned short* khi = ws + 2 * QK;
    unsigned short* klo = ws + 3 * QK;
    unsigned short* vws = ws + 4 * QK;

    proj_kernel<<<dim3(512), dim3(256), 0, stream>>>(
        x, wq, qg, qb, qm, qv, wk, kg, kb, km, kv, wv, vg, vb, vm, vv,
        qhi, qlo, khi, klo, vws);
    attn_kernel<<<dim3(512), dim3(512), 0, stream>>>(
        x, gamma, qhi, qlo, khi, klo, vws, (float*)d_out);
}